// Round 3
// baseline (1094.057 us; speedup 1.0000x reference)
//
#include <hip/hip_runtime.h>
#include <hip/hip_bf16.h>

#define NU 200000
#define NM 80000
#define NT 280000   // NU + NM
#define HD 64
#define FM 20

typedef __attribute__((ext_vector_type(8))) short short8;
typedef __attribute__((ext_vector_type(4))) float floatx4;

__device__ __forceinline__ float bfu2f(unsigned short u) {
    union { unsigned int u; float f; } c; c.u = ((unsigned int)u) << 16; return c.f;
}

__device__ __forceinline__ unsigned short f2bf_raw(float f) {
    union { float f; unsigned int u; } c; c.f = f;
    unsigned int u = c.u + 0x7FFFu + ((c.u >> 16) & 1u);   // round-nearest-even
    return (unsigned short)(u >> 16);
}

// dtype-dispatched float load: isbf ? bf16[i] : f32[i]
__device__ __forceinline__ float ldf(const void* p, long i, int isbf) {
    return isbf ? bfu2f(((const unsigned short*)p)[i]) : ((const float*)p)[i];
}
// index load: is64 ? low word of int64[j] : int32[j]
__device__ __forceinline__ int ldidx(const int* p, long j, int is64) {
    return is64 ? p[2 * j] : p[j];
}

// ---------------- runtime dtype probe -> flags[0]=isbf16, flags[1]=isint64
__global__ void probe_kernel(const void* user_emb, const int* ei, int* flags) {
    int t = threadIdx.x;
    // float dtype: inspect first 128 halfwords as bf16. Real bf16 (sigma=0.05)
    // => every |x| < 1. f32 misread => random low halfwords, some exponent>=135.
    int bad = 0;
    for (int i = t; i < 128; i += 64) {
        unsigned short h = ((const unsigned short*)user_emb)[i];
        unsigned int e = (h >> 7) & 0xFF;
        if (e >= 135) bad = 1;               // |x| >= 256, or Inf/NaN
    }
    unsigned long long mf = __ballot(bad != 0);
    // index width: int64 indices < 2^18 => odd 32-bit words all zero.
    int odd_nonzero = 0;
    if (t < 16 && ei[2 * t + 1] != 0) odd_nonzero = 1;
    unsigned long long mi = __ballot(odd_nonzero != 0);
    if (t == 0) {
        flags[0] = (mf == 0) ? 1 : 0;        // 1 = inputs genuinely bf16
        flags[1] = (mi == 0) ? 1 : 0;        // 1 = indices are int64
    }
}

// ---------------- node feature prep: xb = concat(user_emb, movie_x@lin_W.T + lin_b + movie_emb)  [bf16]
__global__ __launch_bounds__(256) void prep_kernel(
    const void* __restrict__ movie_x,
    const void* __restrict__ user_emb,
    const void* __restrict__ movie_emb,
    const void* __restrict__ lin_W,
    const void* __restrict__ lin_b,
    unsigned short* __restrict__ xb,
    const int* __restrict__ flags)
{
    long i = (long)blockIdx.x * 256 + threadIdx.x;
    if (i >= (long)NT * HD) return;
    int isbf = flags[0];
    long n = i >> 6;
    int h = (int)(i & 63);
    if (n < NU) {
        xb[i] = f2bf_raw(ldf(user_emb, i, isbf));
    } else {
        long m = n - NU;
        float acc = ldf(lin_b, h, isbf) + ldf(movie_emb, m * HD + h, isbf);
        #pragma unroll
        for (int k = 0; k < FM; ++k)
            acc += ldf(movie_x, m * FM + k, isbf) * ldf(lin_W, h * FM + k, isbf);
        xb[i] = f2bf_raw(acc);
    }
}

// ---------------- edge scatter: agg[dst] += x[src] (f32 atomics); deg[dst] += 1 (layer 1 only)
__global__ __launch_bounds__(256) void scatter_kernel(
    const unsigned short* __restrict__ x,
    float* __restrict__ agg,
    float* __restrict__ deg,          // nullptr on layer 2
    const int* __restrict__ ei,
    int E,
    const int* __restrict__ flags)
{
    long g = (long)(blockIdx.x * 256 + threadIdx.x) >> 6;   // edge id (one wave per edge)
    int lane = threadIdx.x & 63;
    if (g >= E) return;
    int is64 = flags[1];
    int s = ldidx(ei, g, is64);
    int d = ldidx(ei, (long)E + g, is64);
    float v = bfu2f(x[(long)s * HD + lane]);
    atomicAdd(&agg[(long)d * HD + lane], v);
    if (deg != nullptr && lane == 0) atomicAdd(&deg[d], 1.0f);
}

// ---------------- combine: out = act( (agg/deg) @ Wl.T + b + xin @ Wr.T )   [in-place: out may == xin]
// one block = one 64-node tile; 4 waves, each does a 16-node row stripe via MFMA 16x16x32 bf16
template <bool RELU>
__global__ __launch_bounds__(256) void combine_kernel(
    const float* __restrict__ agg,
    const float* __restrict__ deg,
    const unsigned short* __restrict__ xin,
    const void* __restrict__ Wl,
    const void* __restrict__ bias,
    const void* __restrict__ Wr,
    unsigned short* __restrict__ out,
    const int* __restrict__ flags)
{
    __shared__ unsigned short lWl[HD * HD];
    __shared__ unsigned short lWr[HD * HD];
    __shared__ unsigned short lmean[HD * HD];
    __shared__ unsigned short lx[HD * HD];
    __shared__ float lb[HD];

    int tid = threadIdx.x;
    int isbf = flags[0];
    for (int i = tid; i < HD * HD; i += 256) {
        lWl[i] = f2bf_raw(ldf(Wl, i, isbf));
        lWr[i] = f2bf_raw(ldf(Wr, i, isbf));
    }
    if (tid < HD) lb[tid] = ldf(bias, tid, isbf);

    int tile = blockIdx.x;                 // 64 nodes per tile; NT = 64*4375 exactly
    long base = (long)tile * HD * HD;      // element offset of this tile's rows
    for (int i = tid; i < HD * HD; i += 256) {
        int node = i >> 6;
        float dg = deg[tile * HD + node];
        float rd = 1.0f / fmaxf(dg, 1.0f);
        lmean[i] = f2bf_raw(agg[base + i] * rd);
        lx[i]    = xin[base + i];
    }
    __syncthreads();      // all reads of this tile's xin complete before any in-place write below

    int w = tid >> 6;          // wave id: rows w*16 .. w*16+15
    int lane = tid & 63;
    int mrow = lane & 15;      // A-frag row / B-frag col / C col
    int quad = lane >> 4;

    // A fragments (mean and x), k-halves 0 and 32
    short8 am0 = *(const short8*)&lmean[(w * 16 + mrow) * HD + quad * 8];
    short8 am1 = *(const short8*)&lmean[(w * 16 + mrow) * HD + 32 + quad * 8];
    short8 ax0 = *(const short8*)&lx[(w * 16 + mrow) * HD + quad * 8];
    short8 ax1 = *(const short8*)&lx[(w * 16 + mrow) * HD + 32 + quad * 8];

    floatx4 acc[4];
    #pragma unroll
    for (int ht = 0; ht < 4; ++ht) {
        int h = ht * 16 + mrow;
        short8 bl0 = *(const short8*)&lWl[h * HD + quad * 8];
        short8 bl1 = *(const short8*)&lWl[h * HD + 32 + quad * 8];
        short8 br0 = *(const short8*)&lWr[h * HD + quad * 8];
        short8 br1 = *(const short8*)&lWr[h * HD + 32 + quad * 8];
        floatx4 a = {0.f, 0.f, 0.f, 0.f};
        a = __builtin_amdgcn_mfma_f32_16x16x32_bf16(am0, bl0, a, 0, 0, 0);
        a = __builtin_amdgcn_mfma_f32_16x16x32_bf16(am1, bl1, a, 0, 0, 0);
        a = __builtin_amdgcn_mfma_f32_16x16x32_bf16(ax0, br0, a, 0, 0, 0);
        a = __builtin_amdgcn_mfma_f32_16x16x32_bf16(ax1, br1, a, 0, 0, 0);
        acc[ht] = a;
    }

    // epilogue: C/D layout col=lane&15 (h), row=quad*4+reg (node)
    #pragma unroll
    for (int ht = 0; ht < 4; ++ht) {
        int h = ht * 16 + mrow;
        float bv = lb[h];
        #pragma unroll
        for (int r = 0; r < 4; ++r) {
            int node = w * 16 + quad * 4 + r;
            float v = acc[ht][r] + bv;
            if (RELU) v = fmaxf(v, 0.0f);
            out[base + node * HD + h] = f2bf_raw(v);
        }
    }
}

// ---------------- final: out[e] = dot(x2[u[e]], x2[NU + m[e]])
__global__ __launch_bounds__(256) void dot_kernel(
    const unsigned short* __restrict__ x2,
    const int* __restrict__ eli,
    void* __restrict__ out,
    int EL,
    const int* __restrict__ flags)
{
    long g = (long)(blockIdx.x * 256 + threadIdx.x) >> 6;
    int lane = threadIdx.x & 63;
    if (g >= EL) return;
    int isbf = flags[0];
    int is64 = flags[1];
    int u = ldidx(eli, g, is64);
    int m = ldidx(eli, (long)EL + g, is64);
    float p = bfu2f(x2[(long)u * HD + lane]) * bfu2f(x2[(long)(NU + m) * HD + lane]);
    #pragma unroll
    for (int off = 32; off > 0; off >>= 1) p += __shfl_down(p, off);
    if (lane == 0) {
        if (isbf) ((unsigned short*)out)[g] = f2bf_raw(p);
        else      ((float*)out)[g] = p;
    }
}

extern "C" void kernel_launch(void* const* d_in, const int* in_sizes, int n_in,
                              void* d_out, int out_size, void* d_ws, size_t ws_size,
                              hipStream_t stream)
{
    const void* movie_x   = d_in[0];
    const void* user_emb  = d_in[1];
    const void* movie_emb = d_in[2];
    const void* lin_W     = d_in[3];
    const void* lin_b     = d_in[4];
    const void* W1l       = d_in[5];
    const void* b1        = d_in[6];
    const void* W1r       = d_in[7];
    const void* W2l       = d_in[8];
    const void* b2        = d_in[9];
    const void* W2r       = d_in[10];
    const int* ei  = (const int*)d_in[11];
    const int* eli = (const int*)d_in[12];
    int E  = in_sizes[11] / 2;   // element counts are dtype-width independent
    int EL = in_sizes[12] / 2;

    // workspace layout:
    //   agg  : f32  NT*HD  (71.68 MB) @ 0
    //   xb   : bf16 NT*HD  (35.84 MB)
    //   deg  : f32  NT     ( 1.12 MB)
    //   flags: int[2]
    float*          agg   = (float*)d_ws;
    unsigned short* xb    = (unsigned short*)((char*)d_ws + (size_t)NT * HD * 4);
    float*          deg   = (float*)((char*)d_ws + (size_t)NT * HD * 6);
    int*            flags = (int*)((char*)d_ws + (size_t)NT * HD * 6 + (size_t)NT * 4);

    const int prep_blocks    = (NT * HD + 255) / 256;       // 70000
    const int scatter_blocks = (E * HD + 255) / 256;        // 312500
    const int tile_blocks    = (NT + 63) / 64;              // 4375
    const int dot_blocks     = (EL * HD + 255) / 256;       // 125000

    // runtime dtype probe (device-side; graph-capture safe)
    probe_kernel<<<1, 64, 0, stream>>>(user_emb, ei, flags);

    // prep node features (bf16 internal storage)
    prep_kernel<<<prep_blocks, 256, 0, stream>>>(movie_x, user_emb, movie_emb, lin_W, lin_b, xb, flags);

    // layer 1
    hipMemsetAsync(agg, 0, (size_t)NT * HD * sizeof(float), stream);
    hipMemsetAsync(deg, 0, (size_t)NT * sizeof(float), stream);
    scatter_kernel<<<scatter_blocks, 256, 0, stream>>>(xb, agg, deg, ei, E, flags);
    combine_kernel<true><<<tile_blocks, 256, 0, stream>>>(agg, deg, xb, W1l, b1, W1r, xb, flags);  // in-place

    // layer 2
    hipMemsetAsync(agg, 0, (size_t)NT * HD * sizeof(float), stream);
    scatter_kernel<<<scatter_blocks, 256, 0, stream>>>(xb, agg, nullptr, ei, E, flags);
    combine_kernel<false><<<tile_blocks, 256, 0, stream>>>(agg, deg, xb, W2l, b2, W2r, xb, flags); // in-place

    // final edge dot products
    dot_kernel<<<dot_blocks, 256, 0, stream>>>(xb, eli, d_out, EL, flags);
}

// Round 4
// 771.638 us; speedup vs baseline: 1.4178x; 1.4178x over previous
//
#include <hip/hip_runtime.h>
#include <hip/hip_bf16.h>

#define NU 200000
#define NM 80000
#define NT 280000   // NU + NM
#define HD 64
#define FM 20

typedef __attribute__((ext_vector_type(8))) short short8;
typedef __attribute__((ext_vector_type(4))) float floatx4;

__device__ __forceinline__ float bfu2f(unsigned short u) {
    union { unsigned int u; float f; } c; c.u = ((unsigned int)u) << 16; return c.f;
}

__device__ __forceinline__ unsigned short f2bf_raw(float f) {
    union { float f; unsigned int u; } c; c.f = f;
    unsigned int u = c.u + 0x7FFFu + ((c.u >> 16) & 1u);   // round-nearest-even
    return (unsigned short)(u >> 16);
}

// dtype-dispatched float load: isbf ? bf16[i] : f32[i]
__device__ __forceinline__ float ldf(const void* p, long i, int isbf) {
    return isbf ? bfu2f(((const unsigned short*)p)[i]) : ((const float*)p)[i];
}
// index load: is64 ? low word of int64[j] : int32[j]
__device__ __forceinline__ int ldidx(const int* p, long j, int is64) {
    return is64 ? p[2 * j] : p[j];
}

// ---------------- runtime dtype probe -> flags[0]=isbf16, flags[1]=isint64
__global__ void probe_kernel(const void* user_emb, const int* ei, int* flags) {
    int t = threadIdx.x;
    int bad = 0;
    for (int i = t; i < 128; i += 64) {
        unsigned short h = ((const unsigned short*)user_emb)[i];
        unsigned int e = (h >> 7) & 0xFF;
        if (e >= 135) bad = 1;               // |x| >= 256, or Inf/NaN -> not real bf16
    }
    unsigned long long mf = __ballot(bad != 0);
    int odd_nonzero = 0;
    if (t < 16 && ei[2 * t + 1] != 0) odd_nonzero = 1;
    unsigned long long mi = __ballot(odd_nonzero != 0);
    if (t == 0) {
        flags[0] = (mf == 0) ? 1 : 0;        // 1 = inputs genuinely bf16
        flags[1] = (mi == 0) ? 1 : 0;        // 1 = indices are int64
    }
}

// ---------------- node feature prep: xb = concat(user_emb, movie_x@lin_W.T + lin_b + movie_emb)  [bf16]
__global__ __launch_bounds__(256) void prep_kernel(
    const void* __restrict__ movie_x,
    const void* __restrict__ user_emb,
    const void* __restrict__ movie_emb,
    const void* __restrict__ lin_W,
    const void* __restrict__ lin_b,
    unsigned short* __restrict__ xb,
    const int* __restrict__ flags)
{
    long i = (long)blockIdx.x * 256 + threadIdx.x;
    if (i >= (long)NT * HD) return;
    int isbf = flags[0];
    long n = i >> 6;
    int h = (int)(i & 63);
    if (n < NU) {
        xb[i] = f2bf_raw(ldf(user_emb, i, isbf));
    } else {
        long m = n - NU;
        float acc = ldf(lin_b, h, isbf) + ldf(movie_emb, m * HD + h, isbf);
        #pragma unroll
        for (int k = 0; k < FM; ++k)
            acc += ldf(movie_x, m * FM + k, isbf) * ldf(lin_W, h * FM + k, isbf);
        xb[i] = f2bf_raw(acc);
    }
}

// ---------------- CSR build ----------------
// K1: degree histogram
__global__ __launch_bounds__(256) void hist_kernel(
    const int* __restrict__ ei, int E, int* __restrict__ cnt, const int* __restrict__ flags)
{
    long e = (long)blockIdx.x * 256 + threadIdx.x;
    if (e >= E) return;
    int d = ldidx(ei, (long)E + e, flags[1]);
    atomicAdd(&cnt[d], 1);
}

// K2: per-256-block sums of cnt
__global__ __launch_bounds__(256) void scan1_kernel(const int* __restrict__ cnt, int* __restrict__ bsum)
{
    __shared__ int s[256];
    int t = threadIdx.x;
    long i = (long)blockIdx.x * 256 + t;
    s[t] = (i < NT) ? cnt[i] : 0;
    __syncthreads();
    for (int off = 128; off > 0; off >>= 1) {
        if (t < off) s[t] += s[t + off];
        __syncthreads();
    }
    if (t == 0) bsum[blockIdx.x] = s[0];
}

// K3: exclusive scan over NB block sums (single block)
__global__ __launch_bounds__(256) void scan2_kernel(int* __restrict__ bsum, int NB)
{
    __shared__ int chunk[256];
    int t = threadIdx.x;
    int per = (NB + 255) / 256;
    int begin = t * per;
    int end = begin + per; if (end > NB) end = NB; if (begin > NB) begin = NB;
    int sum = 0;
    for (int i = begin; i < end; ++i) sum += bsum[i];
    chunk[t] = sum;
    __syncthreads();
    for (int off = 1; off < 256; off <<= 1) {
        int v = chunk[t];
        if (t >= off) v += chunk[t - off];
        __syncthreads();
        chunk[t] = v;
        __syncthreads();
    }
    int run = (t == 0) ? 0 : chunk[t - 1];      // exclusive prefix of this thread's range
    for (int i = begin; i < end; ++i) {
        int v = bsum[i];
        bsum[i] = run;
        run += v;
    }
}

// K4: rowptr[i] = bsum[block] + excl-scan-in-block(cnt); also init fill = rowptr
__global__ __launch_bounds__(256) void scan3_kernel(
    const int* __restrict__ cnt, const int* __restrict__ bsum,
    int* __restrict__ rowptr, int* __restrict__ fill)
{
    __shared__ int s[256];
    int t = threadIdx.x;
    long i = (long)blockIdx.x * 256 + t;
    int v = (i < NT) ? cnt[i] : 0;
    s[t] = v;
    __syncthreads();
    for (int off = 1; off < 256; off <<= 1) {
        int u = s[t];
        if (t >= off) u += s[t - off];
        __syncthreads();
        s[t] = u;
        __syncthreads();
    }
    if (i < NT) {
        int r = bsum[blockIdx.x] + s[t] - v;    // exclusive
        rowptr[i] = r;
        fill[i] = r;
    }
}

// K5: bucket src ids by dst
__global__ __launch_bounds__(256) void fill_kernel(
    const int* __restrict__ ei, int E, int* __restrict__ fill,
    int* __restrict__ srclist, const int* __restrict__ flags)
{
    long e = (long)blockIdx.x * 256 + threadIdx.x;
    if (e >= E) return;
    int is64 = flags[1];
    int sidx = ldidx(ei, e, is64);
    int d = ldidx(ei, (long)E + e, is64);
    int pos = atomicAdd(&fill[d], 1);
    srclist[pos] = sidx;
}

// ---------------- gather: meanb[n] = mean over incoming edges of x[src]  [bf16 out, f32 accum]
__global__ __launch_bounds__(256) void gather_mean(
    const unsigned short* __restrict__ x,
    const int* __restrict__ rowptr,
    const int* __restrict__ cnt,
    const int* __restrict__ srclist,
    unsigned short* __restrict__ meanb)
{
    int wid = (int)(((long)blockIdx.x * 256 + threadIdx.x) >> 6);   // node id
    int lane = threadIdx.x & 63;
    if (wid >= NT) return;
    int beg = rowptr[wid];
    int deg = cnt[wid];
    float acc = 0.f;
    int j0 = 0;
    while (j0 < deg) {
        int m = deg - j0; if (m > 64) m = 64;
        int sv = (lane < m) ? srclist[beg + j0 + lane] : 0;
        int j = 0;
        for (; j + 4 <= m; j += 4) {
            int s0 = __shfl(sv, j);
            int s1 = __shfl(sv, j + 1);
            int s2 = __shfl(sv, j + 2);
            int s3 = __shfl(sv, j + 3);
            float v0 = bfu2f(x[(long)s0 * HD + lane]);
            float v1 = bfu2f(x[(long)s1 * HD + lane]);
            float v2 = bfu2f(x[(long)s2 * HD + lane]);
            float v3 = bfu2f(x[(long)s3 * HD + lane]);
            acc += v0 + v1 + v2 + v3;
        }
        for (; j < m; ++j) {
            int s = __shfl(sv, j);
            acc += bfu2f(x[(long)s * HD + lane]);
        }
        j0 += m;
    }
    float mean = acc / fmaxf((float)deg, 1.0f);
    meanb[(long)wid * HD + lane] = f2bf_raw(mean);
}

// ---------------- combine: out = act( mean @ Wl.T + b + xin @ Wr.T )   [in-place: out may == xin]
template <bool RELU>
__global__ __launch_bounds__(256) void combine_kernel(
    const unsigned short* __restrict__ meanb,
    const unsigned short* __restrict__ xin,
    const void* __restrict__ Wl,
    const void* __restrict__ bias,
    const void* __restrict__ Wr,
    unsigned short* __restrict__ out,
    const int* __restrict__ flags)
{
    __shared__ unsigned short lWl[HD * HD];
    __shared__ unsigned short lWr[HD * HD];
    __shared__ unsigned short lmean[HD * HD];
    __shared__ unsigned short lx[HD * HD];
    __shared__ float lb[HD];

    int tid = threadIdx.x;
    int isbf = flags[0];
    for (int i = tid; i < HD * HD; i += 256) {
        lWl[i] = f2bf_raw(ldf(Wl, i, isbf));
        lWr[i] = f2bf_raw(ldf(Wr, i, isbf));
    }
    if (tid < HD) lb[tid] = ldf(bias, tid, isbf);

    int tile = blockIdx.x;                 // 64 nodes per tile; NT = 64*4375 exactly
    long base = (long)tile * HD * HD;
    for (int i = tid; i < HD * HD; i += 256) {
        lmean[i] = meanb[base + i];
        lx[i]    = xin[base + i];
    }
    __syncthreads();      // all reads of this tile's xin complete before any in-place write below

    int w = tid >> 6;
    int lane = tid & 63;
    int mrow = lane & 15;
    int quad = lane >> 4;

    short8 am0 = *(const short8*)&lmean[(w * 16 + mrow) * HD + quad * 8];
    short8 am1 = *(const short8*)&lmean[(w * 16 + mrow) * HD + 32 + quad * 8];
    short8 ax0 = *(const short8*)&lx[(w * 16 + mrow) * HD + quad * 8];
    short8 ax1 = *(const short8*)&lx[(w * 16 + mrow) * HD + 32 + quad * 8];

    floatx4 acc[4];
    #pragma unroll
    for (int ht = 0; ht < 4; ++ht) {
        int h = ht * 16 + mrow;
        short8 bl0 = *(const short8*)&lWl[h * HD + quad * 8];
        short8 bl1 = *(const short8*)&lWl[h * HD + 32 + quad * 8];
        short8 br0 = *(const short8*)&lWr[h * HD + quad * 8];
        short8 br1 = *(const short8*)&lWr[h * HD + 32 + quad * 8];
        floatx4 a = {0.f, 0.f, 0.f, 0.f};
        a = __builtin_amdgcn_mfma_f32_16x16x32_bf16(am0, bl0, a, 0, 0, 0);
        a = __builtin_amdgcn_mfma_f32_16x16x32_bf16(am1, bl1, a, 0, 0, 0);
        a = __builtin_amdgcn_mfma_f32_16x16x32_bf16(ax0, br0, a, 0, 0, 0);
        a = __builtin_amdgcn_mfma_f32_16x16x32_bf16(ax1, br1, a, 0, 0, 0);
        acc[ht] = a;
    }

    #pragma unroll
    for (int ht = 0; ht < 4; ++ht) {
        int h = ht * 16 + mrow;
        float bv = lb[h];
        #pragma unroll
        for (int r = 0; r < 4; ++r) {
            int node = w * 16 + quad * 4 + r;
            float v = acc[ht][r] + bv;
            if (RELU) v = fmaxf(v, 0.0f);
            out[base + node * HD + h] = f2bf_raw(v);
        }
    }
}

// ---------------- final: out[e] = dot(x2[u[e]], x2[NU + m[e]])
__global__ __launch_bounds__(256) void dot_kernel(
    const unsigned short* __restrict__ x2,
    const int* __restrict__ eli,
    void* __restrict__ out,
    int EL,
    const int* __restrict__ flags)
{
    long g = ((long)blockIdx.x * 256 + threadIdx.x) >> 6;
    int lane = threadIdx.x & 63;
    if (g >= EL) return;
    int isbf = flags[0];
    int is64 = flags[1];
    int u = ldidx(eli, g, is64);
    int m = ldidx(eli, (long)EL + g, is64);
    float p = bfu2f(x2[(long)u * HD + lane]) * bfu2f(x2[(long)(NU + m) * HD + lane]);
    #pragma unroll
    for (int off = 32; off > 0; off >>= 1) p += __shfl_down(p, off);
    if (lane == 0) {
        if (isbf) ((unsigned short*)out)[g] = f2bf_raw(p);
        else      ((float*)out)[g] = p;
    }
}

extern "C" void kernel_launch(void* const* d_in, const int* in_sizes, int n_in,
                              void* d_out, int out_size, void* d_ws, size_t ws_size,
                              hipStream_t stream)
{
    const void* movie_x   = d_in[0];
    const void* user_emb  = d_in[1];
    const void* movie_emb = d_in[2];
    const void* lin_W     = d_in[3];
    const void* lin_b     = d_in[4];
    const void* W1l       = d_in[5];
    const void* b1        = d_in[6];
    const void* W1r       = d_in[7];
    const void* W2l       = d_in[8];
    const void* b2        = d_in[9];
    const void* W2r       = d_in[10];
    const int* ei  = (const int*)d_in[11];
    const int* eli = (const int*)d_in[12];
    int E  = in_sizes[11] / 2;
    int EL = in_sizes[12] / 2;

    const int NB = (NT + 255) / 256;     // 1094 scan blocks

    // workspace layout (~80 MB)
    char* w = (char*)d_ws;
    unsigned short* xb      = (unsigned short*)w;  w += (size_t)NT * HD * 2;  // 35.84 MB
    unsigned short* meanb   = (unsigned short*)w;  w += (size_t)NT * HD * 2;  // 35.84 MB
    int*            cnt     = (int*)w;             w += (size_t)NT * 4;       //  1.12 MB
    int*            rowptr  = (int*)w;             w += (size_t)NT * 4;
    int*            fillp   = (int*)w;             w += (size_t)NT * 4;
    int*            srclist = (int*)w;             w += (size_t)E * 4;        //  5.0 MB
    int*            bsum    = (int*)w;             w += (size_t)NB * 4;
    int*            flags   = (int*)w;

    const int prep_blocks    = (NT * HD + 255) / 256;   // 70000
    const int edge_blocks    = (E + 255) / 256;         // 4883
    const int node_blocks    = (NT * HD + 255) / 256;   // one wave per node
    const int tile_blocks    = NT / 64;                 // 4375
    const int dot_blocks     = (EL * HD + 255) / 256;   // 125000

    // dtype probe (device-side, graph-capture safe)
    probe_kernel<<<1, 64, 0, stream>>>(user_emb, ei, flags);

    // node features (bf16)
    prep_kernel<<<prep_blocks, 256, 0, stream>>>(movie_x, user_emb, movie_emb, lin_W, lin_b, xb, flags);

    // CSR build (once; reused by both layers)
    hipMemsetAsync(cnt, 0, (size_t)NT * 4, stream);
    hist_kernel<<<edge_blocks, 256, 0, stream>>>(ei, E, cnt, flags);
    scan1_kernel<<<NB, 256, 0, stream>>>(cnt, bsum);
    scan2_kernel<<<1, 256, 0, stream>>>(bsum, NB);
    scan3_kernel<<<NB, 256, 0, stream>>>(cnt, bsum, rowptr, fillp);
    fill_kernel<<<edge_blocks, 256, 0, stream>>>(ei, E, fillp, srclist, flags);

    // layer 1
    gather_mean<<<node_blocks, 256, 0, stream>>>(xb, rowptr, cnt, srclist, meanb);
    combine_kernel<true><<<tile_blocks, 256, 0, stream>>>(meanb, xb, W1l, b1, W1r, xb, flags);   // in-place

    // layer 2
    gather_mean<<<node_blocks, 256, 0, stream>>>(xb, rowptr, cnt, srclist, meanb);
    combine_kernel<false><<<tile_blocks, 256, 0, stream>>>(meanb, xb, W2l, b2, W2r, xb, flags);  // in-place

    // final edge dot products
    dot_kernel<<<dot_blocks, 256, 0, stream>>>(xb, eli, d_out, EL, flags);
}

// Round 5
// 617.925 us; speedup vs baseline: 1.7705x; 1.2488x over previous
//
#include <hip/hip_runtime.h>
#include <hip/hip_bf16.h>

#define NU 200000
#define NM 80000
#define NT 280000   // NU + NM
#define HD 64
#define FM 20

typedef __attribute__((ext_vector_type(8))) short short8;
typedef __attribute__((ext_vector_type(4))) float floatx4;

__device__ __forceinline__ float bfu2f(unsigned short u) {
    union { unsigned int u; float f; } c; c.u = ((unsigned int)u) << 16; return c.f;
}

__device__ __forceinline__ unsigned short f2bf_raw(float f) {
    union { float f; unsigned int u; } c; c.f = f;
    unsigned int u = c.u + 0x7FFFu + ((c.u >> 16) & 1u);   // round-nearest-even
    return (unsigned short)(u >> 16);
}

__device__ __forceinline__ float ldf(const void* p, long i, int isbf) {
    return isbf ? bfu2f(((const unsigned short*)p)[i]) : ((const float*)p)[i];
}
__device__ __forceinline__ int ldidx(const int* p, long j, int is64) {
    return is64 ? p[2 * j] : p[j];
}

// ---------------- runtime dtype probe -> flags[0]=isbf16, flags[1]=isint64
__global__ void probe_kernel(const void* user_emb, const int* ei, int* flags) {
    int t = threadIdx.x;
    int bad = 0;
    for (int i = t; i < 128; i += 64) {
        unsigned short h = ((const unsigned short*)user_emb)[i];
        unsigned int e = (h >> 7) & 0xFF;
        if (e >= 135) bad = 1;               // |x| >= 256, or Inf/NaN -> not real bf16
    }
    unsigned long long mf = __ballot(bad != 0);
    int odd_nonzero = 0;
    if (t < 16 && ei[2 * t + 1] != 0) odd_nonzero = 1;
    unsigned long long mi = __ballot(odd_nonzero != 0);
    if (t == 0) {
        flags[0] = (mf == 0) ? 1 : 0;
        flags[1] = (mi == 0) ? 1 : 0;
    }
}

// ---------------- prep A: user rows, vectorized copy/convert (8 elems/thread)
__global__ __launch_bounds__(256) void prep_user(
    const void* __restrict__ user_emb,
    unsigned short* __restrict__ xb,
    const int* __restrict__ flags)
{
    long t = (long)blockIdx.x * 256 + threadIdx.x;        // t < NU*HD/8 = 1.6M exactly
    int isbf = flags[0];
    if (isbf) {
        ((short8*)xb)[t] = ((const short8*)user_emb)[t];
    } else {
        floatx4 a = ((const floatx4*)user_emb)[2 * t];
        floatx4 b = ((const floatx4*)user_emb)[2 * t + 1];
        short8 r;
        r[0] = (short)f2bf_raw(a[0]); r[1] = (short)f2bf_raw(a[1]);
        r[2] = (short)f2bf_raw(a[2]); r[3] = (short)f2bf_raw(a[3]);
        r[4] = (short)f2bf_raw(b[0]); r[5] = (short)f2bf_raw(b[1]);
        r[6] = (short)f2bf_raw(b[2]); r[7] = (short)f2bf_raw(b[3]);
        ((short8*)xb)[t] = r;
    }
}

// ---------------- prep B: movie rows. lin_W transposed in LDS; movie_x row via shfl.
__global__ __launch_bounds__(256) void prep_movie(
    const void* __restrict__ movie_x,
    const void* __restrict__ movie_emb,
    const void* __restrict__ lin_W,
    const void* __restrict__ lin_b,
    unsigned short* __restrict__ xb,
    const int* __restrict__ flags)
{
    __shared__ float lWT[FM * HD];   // [k][h] layout -> conflict-free reads
    __shared__ float lb[HD];
    int tid = threadIdx.x;
    int isbf = flags[0];
    for (int i = tid; i < FM * HD; i += 256) {
        int k = i >> 6, h = i & 63;
        lWT[i] = ldf(lin_W, (long)h * FM + k, isbf);
    }
    if (tid < HD) lb[tid] = ldf(lin_b, tid, isbf);
    __syncthreads();

    int m = (blockIdx.x * 256 + tid) >> 6;    // movie id, one wave per movie
    int lane = tid & 63;
    if (m >= NM) return;
    float mxv = (lane < FM) ? ldf(movie_x, (long)m * FM + lane, isbf) : 0.f;
    float acc = lb[lane] + ldf(movie_emb, (long)m * HD + lane, isbf);
    #pragma unroll
    for (int k = 0; k < FM; ++k)
        acc += __shfl(mxv, k) * lWT[k * HD + lane];
    xb[(long)(NU + m) * HD + lane] = f2bf_raw(acc);
}

// ---------------- CSR build ----------------
__global__ __launch_bounds__(256) void hist_kernel(
    const int* __restrict__ ei, int E, int* __restrict__ cnt, const int* __restrict__ flags)
{
    long e = (long)blockIdx.x * 256 + threadIdx.x;
    if (e >= E) return;
    int d = ldidx(ei, (long)E + e, flags[1]);
    atomicAdd(&cnt[d], 1);
}

__global__ __launch_bounds__(256) void scan1_kernel(const int* __restrict__ cnt, int* __restrict__ bsum)
{
    __shared__ int s[256];
    int t = threadIdx.x;
    long i = (long)blockIdx.x * 256 + t;
    s[t] = (i < NT) ? cnt[i] : 0;
    __syncthreads();
    for (int off = 128; off > 0; off >>= 1) {
        if (t < off) s[t] += s[t + off];
        __syncthreads();
    }
    if (t == 0) bsum[blockIdx.x] = s[0];
}

__global__ __launch_bounds__(256) void scan2_kernel(int* __restrict__ bsum, int NB)
{
    __shared__ int chunk[256];
    int t = threadIdx.x;
    int per = (NB + 255) / 256;
    int begin = t * per;
    int end = begin + per; if (end > NB) end = NB; if (begin > NB) begin = NB;
    int sum = 0;
    for (int i = begin; i < end; ++i) sum += bsum[i];
    chunk[t] = sum;
    __syncthreads();
    for (int off = 1; off < 256; off <<= 1) {
        int v = chunk[t];
        if (t >= off) v += chunk[t - off];
        __syncthreads();
        chunk[t] = v;
        __syncthreads();
    }
    int run = (t == 0) ? 0 : chunk[t - 1];
    for (int i = begin; i < end; ++i) {
        int v = bsum[i];
        bsum[i] = run;
        run += v;
    }
}

__global__ __launch_bounds__(256) void scan3_kernel(
    const int* __restrict__ cnt, const int* __restrict__ bsum,
    int* __restrict__ rowptr, int* __restrict__ fill)
{
    __shared__ int s[256];
    int t = threadIdx.x;
    long i = (long)blockIdx.x * 256 + t;
    int v = (i < NT) ? cnt[i] : 0;
    s[t] = v;
    __syncthreads();
    for (int off = 1; off < 256; off <<= 1) {
        int u = s[t];
        if (t >= off) u += s[t - off];
        __syncthreads();
        s[t] = u;
        __syncthreads();
    }
    if (i < NT) {
        int r = bsum[blockIdx.x] + s[t] - v;
        rowptr[i] = r;
        fill[i] = r;
    }
}

__global__ __launch_bounds__(256) void fill_kernel(
    const int* __restrict__ ei, int E, int* __restrict__ fill,
    int* __restrict__ srclist, const int* __restrict__ flags)
{
    long e = (long)blockIdx.x * 256 + threadIdx.x;
    if (e >= E) return;
    int is64 = flags[1];
    int sidx = ldidx(ei, e, is64);
    int d = ldidx(ei, (long)E + e, is64);
    int pos = atomicAdd(&fill[d], 1);
    srclist[pos] = sidx;
}

// ---------------- gather: meanb[n] = mean over incoming edges of x[src]  [8 rows in flight]
__global__ __launch_bounds__(256) void gather_mean(
    const unsigned short* __restrict__ x,
    const int* __restrict__ rowptr,
    const int* __restrict__ cnt,
    const int* __restrict__ srclist,
    unsigned short* __restrict__ meanb)
{
    int wid = (int)(((long)blockIdx.x * 256 + threadIdx.x) >> 6);   // node id
    int lane = threadIdx.x & 63;
    if (wid >= NT) return;
    int beg = rowptr[wid];
    int deg = cnt[wid];
    float acc = 0.f;
    int j0 = 0;
    while (j0 < deg) {
        int m = deg - j0; if (m > 64) m = 64;
        int sv = (lane < m) ? srclist[beg + j0 + lane] : 0;
        int j = 0;
        while (j < m) {
            int c = m - j; if (c > 8) c = 8;
            float v[8];
            #pragma unroll
            for (int q = 0; q < 8; ++q) {                 // issue up to 8 independent loads
                int idx = j + ((q < c) ? q : 0);
                int s = __shfl(sv, idx);
                v[q] = bfu2f(x[(long)s * HD + lane]);
            }
            #pragma unroll
            for (int q = 0; q < 8; ++q) if (q < c) acc += v[q];
            j += c;
        }
        j0 += m;
    }
    float mean = acc / fmaxf((float)deg, 1.0f);
    meanb[(long)wid * HD + lane] = f2bf_raw(mean);
}

// ---------------- combine: out = act( mean @ Wl.T + b + xin @ Wr.T )   [in-place: out may == xin]
template <bool RELU>
__global__ __launch_bounds__(256) void combine_kernel(
    const unsigned short* __restrict__ meanb,
    const unsigned short* __restrict__ xin,
    const void* __restrict__ Wl,
    const void* __restrict__ bias,
    const void* __restrict__ Wr,
    unsigned short* __restrict__ out,
    const int* __restrict__ flags)
{
    __shared__ short8 lWl8[HD * HD / 8];
    __shared__ short8 lWr8[HD * HD / 8];
    __shared__ short8 lmean8[HD * HD / 8];
    __shared__ short8 lx8[HD * HD / 8];
    __shared__ float lb[HD];
    unsigned short* lWl  = (unsigned short*)lWl8;
    unsigned short* lWr  = (unsigned short*)lWr8;
    unsigned short* lmean = (unsigned short*)lmean8;
    unsigned short* lx   = (unsigned short*)lx8;

    int tid = threadIdx.x;
    int isbf = flags[0];
    if (isbf) {
        const short8* wl8 = (const short8*)Wl;
        const short8* wr8 = (const short8*)Wr;
        for (int i = tid; i < HD * HD / 8; i += 256) { lWl8[i] = wl8[i]; lWr8[i] = wr8[i]; }
    } else {
        const floatx4* wlf = (const floatx4*)Wl;
        const floatx4* wrf = (const floatx4*)Wr;
        for (int i = tid; i < HD * HD / 8; i += 256) {
            floatx4 a = wlf[2 * i], b = wlf[2 * i + 1];
            short8 r;
            r[0]=(short)f2bf_raw(a[0]); r[1]=(short)f2bf_raw(a[1]); r[2]=(short)f2bf_raw(a[2]); r[3]=(short)f2bf_raw(a[3]);
            r[4]=(short)f2bf_raw(b[0]); r[5]=(short)f2bf_raw(b[1]); r[6]=(short)f2bf_raw(b[2]); r[7]=(short)f2bf_raw(b[3]);
            lWl8[i] = r;
            a = wrf[2 * i]; b = wrf[2 * i + 1];
            r[0]=(short)f2bf_raw(a[0]); r[1]=(short)f2bf_raw(a[1]); r[2]=(short)f2bf_raw(a[2]); r[3]=(short)f2bf_raw(a[3]);
            r[4]=(short)f2bf_raw(b[0]); r[5]=(short)f2bf_raw(b[1]); r[6]=(short)f2bf_raw(b[2]); r[7]=(short)f2bf_raw(b[3]);
            lWr8[i] = r;
        }
    }
    if (tid < HD) lb[tid] = ldf(bias, tid, isbf);

    int tile = blockIdx.x;                 // 64 nodes per tile; NT = 64*4375 exactly
    long base = (long)tile * HD * HD;
    const short8* mv = (const short8*)(meanb + base);
    const short8* xv = (const short8*)(xin + base);
    for (int i = tid; i < HD * HD / 8; i += 256) { lmean8[i] = mv[i]; lx8[i] = xv[i]; }
    __syncthreads();      // all reads of this tile's xin complete before any in-place write below

    int w = tid >> 6;
    int lane = tid & 63;
    int mrow = lane & 15;
    int quad = lane >> 4;

    short8 am0 = *(const short8*)&lmean[(w * 16 + mrow) * HD + quad * 8];
    short8 am1 = *(const short8*)&lmean[(w * 16 + mrow) * HD + 32 + quad * 8];
    short8 ax0 = *(const short8*)&lx[(w * 16 + mrow) * HD + quad * 8];
    short8 ax1 = *(const short8*)&lx[(w * 16 + mrow) * HD + 32 + quad * 8];

    floatx4 acc[4];
    #pragma unroll
    for (int ht = 0; ht < 4; ++ht) {
        int h = ht * 16 + mrow;
        short8 bl0 = *(const short8*)&lWl[h * HD + quad * 8];
        short8 bl1 = *(const short8*)&lWl[h * HD + 32 + quad * 8];
        short8 br0 = *(const short8*)&lWr[h * HD + quad * 8];
        short8 br1 = *(const short8*)&lWr[h * HD + 32 + quad * 8];
        floatx4 a = {0.f, 0.f, 0.f, 0.f};
        a = __builtin_amdgcn_mfma_f32_16x16x32_bf16(am0, bl0, a, 0, 0, 0);
        a = __builtin_amdgcn_mfma_f32_16x16x32_bf16(am1, bl1, a, 0, 0, 0);
        a = __builtin_amdgcn_mfma_f32_16x16x32_bf16(ax0, br0, a, 0, 0, 0);
        a = __builtin_amdgcn_mfma_f32_16x16x32_bf16(ax1, br1, a, 0, 0, 0);
        acc[ht] = a;
    }

    #pragma unroll
    for (int ht = 0; ht < 4; ++ht) {
        int h = ht * 16 + mrow;
        float bv = lb[h];
        #pragma unroll
        for (int r = 0; r < 4; ++r) {
            int node = w * 16 + quad * 4 + r;
            float v = acc[ht][r] + bv;
            if (RELU) v = fmaxf(v, 0.0f);
            out[base + node * HD + h] = f2bf_raw(v);
        }
    }
}

// ---------------- final: out[e] = dot(x2[u[e]], x2[NU + m[e]])
__global__ __launch_bounds__(256) void dot_kernel(
    const unsigned short* __restrict__ x2,
    const int* __restrict__ eli,
    void* __restrict__ out,
    int EL,
    const int* __restrict__ flags)
{
    long g = ((long)blockIdx.x * 256 + threadIdx.x) >> 6;
    int lane = threadIdx.x & 63;
    if (g >= EL) return;
    int isbf = flags[0];
    int is64 = flags[1];
    int u = ldidx(eli, g, is64);
    int m = ldidx(eli, (long)EL + g, is64);
    float p = bfu2f(x2[(long)u * HD + lane]) * bfu2f(x2[(long)(NU + m) * HD + lane]);
    #pragma unroll
    for (int off = 32; off > 0; off >>= 1) p += __shfl_down(p, off);
    if (lane == 0) {
        if (isbf) ((unsigned short*)out)[g] = f2bf_raw(p);
        else      ((float*)out)[g] = p;
    }
}

extern "C" void kernel_launch(void* const* d_in, const int* in_sizes, int n_in,
                              void* d_out, int out_size, void* d_ws, size_t ws_size,
                              hipStream_t stream)
{
    const void* movie_x   = d_in[0];
    const void* user_emb  = d_in[1];
    const void* movie_emb = d_in[2];
    const void* lin_W     = d_in[3];
    const void* lin_b     = d_in[4];
    const void* W1l       = d_in[5];
    const void* b1        = d_in[6];
    const void* W1r       = d_in[7];
    const void* W2l       = d_in[8];
    const void* b2        = d_in[9];
    const void* W2r       = d_in[10];
    const int* ei  = (const int*)d_in[11];
    const int* eli = (const int*)d_in[12];
    int E  = in_sizes[11] / 2;
    int EL = in_sizes[12] / 2;

    const int NB = (NT + 255) / 256;     // 1094 scan blocks

    char* w = (char*)d_ws;
    unsigned short* xb      = (unsigned short*)w;  w += (size_t)NT * HD * 2;
    unsigned short* meanb   = (unsigned short*)w;  w += (size_t)NT * HD * 2;
    int*            cnt     = (int*)w;             w += (size_t)NT * 4;
    int*            rowptr  = (int*)w;             w += (size_t)NT * 4;
    int*            fillp   = (int*)w;             w += (size_t)NT * 4;
    int*            srclist = (int*)w;             w += (size_t)E * 4;
    int*            bsum    = (int*)w;             w += (size_t)NB * 4;
    int*            flags   = (int*)w;

    const int user_blocks  = (NU * HD / 8) / 256;       // 6250 exactly
    const int movie_blocks = (NM * 64 + 255) / 256;     // 20000 (wave per movie)
    const int edge_blocks  = (E + 255) / 256;
    const int node_blocks  = (NT * HD + 255) / 256;
    const int tile_blocks  = NT / 64;                   // 4375
    const int dot_blocks   = (EL * HD + 255) / 256;     // 125000

    probe_kernel<<<1, 64, 0, stream>>>(user_emb, ei, flags);

    prep_user<<<user_blocks, 256, 0, stream>>>(user_emb, xb, flags);
    prep_movie<<<movie_blocks, 256, 0, stream>>>(movie_x, movie_emb, lin_W, lin_b, xb, flags);

    // CSR build (once; reused by both layers)
    hipMemsetAsync(cnt, 0, (size_t)NT * 4, stream);
    hist_kernel<<<edge_blocks, 256, 0, stream>>>(ei, E, cnt, flags);
    scan1_kernel<<<NB, 256, 0, stream>>>(cnt, bsum);
    scan2_kernel<<<1, 256, 0, stream>>>(bsum, NB);
    scan3_kernel<<<NB, 256, 0, stream>>>(cnt, bsum, rowptr, fillp);
    fill_kernel<<<edge_blocks, 256, 0, stream>>>(ei, E, fillp, srclist, flags);

    // layer 1
    gather_mean<<<node_blocks, 256, 0, stream>>>(xb, rowptr, cnt, srclist, meanb);
    combine_kernel<true><<<tile_blocks, 256, 0, stream>>>(meanb, xb, W1l, b1, W1r, xb, flags);

    // layer 2
    gather_mean<<<node_blocks, 256, 0, stream>>>(xb, rowptr, cnt, srclist, meanb);
    combine_kernel<false><<<tile_blocks, 256, 0, stream>>>(meanb, xb, W2l, b2, W2r, xb, flags);

    // final edge dot products
    dot_kernel<<<dot_blocks, 256, 0, stream>>>(xb, eli, d_out, EL, flags);
}

// Round 6
// 594.961 us; speedup vs baseline: 1.8389x; 1.0386x over previous
//
#include <hip/hip_runtime.h>
#include <hip/hip_bf16.h>

#define NU 200000
#define NM 80000
#define NT 280000   // NU + NM
#define HD 64
#define FM 20

#define BSHIFT 10
#define NBUCK ((NT + 1023) >> 10)   // 274 buckets of 1024 nodes
#define CHUNK 8192

typedef __attribute__((ext_vector_type(8))) short short8;
typedef __attribute__((ext_vector_type(4))) float floatx4;

__device__ __forceinline__ float bfu2f(unsigned short u) {
    union { unsigned int u; float f; } c; c.u = ((unsigned int)u) << 16; return c.f;
}

__device__ __forceinline__ unsigned short f2bf_raw(float f) {
    union { float f; unsigned int u; } c; c.f = f;
    unsigned int u = c.u + 0x7FFFu + ((c.u >> 16) & 1u);   // round-nearest-even
    return (unsigned short)(u >> 16);
}

__device__ __forceinline__ float ldf(const void* p, long i, int isbf) {
    return isbf ? bfu2f(((const unsigned short*)p)[i]) : ((const float*)p)[i];
}
__device__ __forceinline__ int ldidx(const int* p, long j, int is64) {
    return is64 ? p[2 * j] : p[j];
}

// ---------------- runtime dtype probe -> flags[0]=isbf16, flags[1]=isint64
__global__ void probe_kernel(const void* user_emb, const int* ei, int* flags) {
    int t = threadIdx.x;
    int bad = 0;
    for (int i = t; i < 128; i += 64) {
        unsigned short h = ((const unsigned short*)user_emb)[i];
        unsigned int e = (h >> 7) & 0xFF;
        if (e >= 135) bad = 1;               // |x| >= 256, or Inf/NaN -> not real bf16
    }
    unsigned long long mf = __ballot(bad != 0);
    int odd_nonzero = 0;
    if (t < 16 && ei[2 * t + 1] != 0) odd_nonzero = 1;
    unsigned long long mi = __ballot(odd_nonzero != 0);
    if (t == 0) {
        flags[0] = (mf == 0) ? 1 : 0;
        flags[1] = (mi == 0) ? 1 : 0;
    }
}

// ---------------- prep A: user rows, vectorized copy/convert (8 elems/thread)
__global__ __launch_bounds__(256) void prep_user(
    const void* __restrict__ user_emb,
    unsigned short* __restrict__ xb,
    const int* __restrict__ flags)
{
    long t = (long)blockIdx.x * 256 + threadIdx.x;        // t < NU*HD/8 = 1.6M exactly
    int isbf = flags[0];
    if (isbf) {
        ((short8*)xb)[t] = ((const short8*)user_emb)[t];
    } else {
        floatx4 a = ((const floatx4*)user_emb)[2 * t];
        floatx4 b = ((const floatx4*)user_emb)[2 * t + 1];
        short8 r;
        r[0] = (short)f2bf_raw(a[0]); r[1] = (short)f2bf_raw(a[1]);
        r[2] = (short)f2bf_raw(a[2]); r[3] = (short)f2bf_raw(a[3]);
        r[4] = (short)f2bf_raw(b[0]); r[5] = (short)f2bf_raw(b[1]);
        r[6] = (short)f2bf_raw(b[2]); r[7] = (short)f2bf_raw(b[3]);
        ((short8*)xb)[t] = r;
    }
}

// ---------------- prep B: movie rows. lin_W transposed in LDS; movie_x row via shfl.
__global__ __launch_bounds__(256) void prep_movie(
    const void* __restrict__ movie_x,
    const void* __restrict__ movie_emb,
    const void* __restrict__ lin_W,
    const void* __restrict__ lin_b,
    unsigned short* __restrict__ xb,
    const int* __restrict__ flags)
{
    __shared__ float lWT[FM * HD];   // [k][h] layout -> conflict-free reads
    __shared__ float lb[HD];
    int tid = threadIdx.x;
    int isbf = flags[0];
    for (int i = tid; i < FM * HD; i += 256) {
        int k = i >> 6, h = i & 63;
        lWT[i] = ldf(lin_W, (long)h * FM + k, isbf);
    }
    if (tid < HD) lb[tid] = ldf(lin_b, tid, isbf);
    __syncthreads();

    int m = (blockIdx.x * 256 + tid) >> 6;    // movie id, one wave per movie
    int lane = tid & 63;
    if (m >= NM) return;
    float mxv = (lane < FM) ? ldf(movie_x, (long)m * FM + lane, isbf) : 0.f;
    float acc = lb[lane] + ldf(movie_emb, (long)m * HD + lane, isbf);
    #pragma unroll
    for (int k = 0; k < FM; ++k)
        acc += __shfl(mxv, k) * lWT[k * HD + lane];
    xb[(long)(NU + m) * HD + lane] = f2bf_raw(acc);
}

// ---------------- CSR build ----------------
__global__ __launch_bounds__(256) void hist_kernel(
    const int* __restrict__ ei, int E, int* __restrict__ cnt, const int* __restrict__ flags)
{
    long e = (long)blockIdx.x * 256 + threadIdx.x;
    if (e >= E) return;
    int d = ldidx(ei, (long)E + e, flags[1]);
    atomicAdd(&cnt[d], 1);
}

__global__ __launch_bounds__(256) void scan1_kernel(const int* __restrict__ cnt, int* __restrict__ bsum)
{
    __shared__ int s[256];
    int t = threadIdx.x;
    long i = (long)blockIdx.x * 256 + t;
    s[t] = (i < NT) ? cnt[i] : 0;
    __syncthreads();
    for (int off = 128; off > 0; off >>= 1) {
        if (t < off) s[t] += s[t + off];
        __syncthreads();
    }
    if (t == 0) bsum[blockIdx.x] = s[0];
}

__global__ __launch_bounds__(256) void scan2_kernel(int* __restrict__ bsum, int NB)
{
    __shared__ int chunk[256];
    int t = threadIdx.x;
    int per = (NB + 255) / 256;
    int begin = t * per;
    int end = begin + per; if (end > NB) end = NB; if (begin > NB) begin = NB;
    int sum = 0;
    for (int i = begin; i < end; ++i) sum += bsum[i];
    chunk[t] = sum;
    __syncthreads();
    for (int off = 1; off < 256; off <<= 1) {
        int v = chunk[t];
        if (t >= off) v += chunk[t - off];
        __syncthreads();
        chunk[t] = v;
        __syncthreads();
    }
    int run = (t == 0) ? 0 : chunk[t - 1];
    for (int i = begin; i < end; ++i) {
        int v = bsum[i];
        bsum[i] = run;
        run += v;
    }
}

__global__ __launch_bounds__(256) void scan3_kernel(
    const int* __restrict__ cnt, const int* __restrict__ bsum,
    int* __restrict__ rowptr)
{
    __shared__ int s[256];
    int t = threadIdx.x;
    long i = (long)blockIdx.x * 256 + t;
    int v = (i < NT) ? cnt[i] : 0;
    s[t] = v;
    __syncthreads();
    for (int off = 1; off < 256; off <<= 1) {
        int u = s[t];
        if (t >= off) u += s[t - off];
        __syncthreads();
        s[t] = u;
        __syncthreads();
    }
    if (i < NT) rowptr[i] = bsum[blockIdx.x] + s[t] - v;   // exclusive
}

// ---------------- bucket pass: group edges by dst>>10 into packed buffer (coalesced runs)
// packed entry: (src << 10) | (dst & 1023); bucket b's region = [rowptr[b<<10], ...)
__global__ __launch_bounds__(256) void bucket_kernel(
    const int* __restrict__ ei, int E,
    const int* __restrict__ rowptr,
    int* __restrict__ bfill,           // NBUCK cursors, pre-zeroed
    int* __restrict__ packed,
    const int* __restrict__ flags)
{
    __shared__ int hist[NBUCK];
    __shared__ int loff[NBUCK + 1];
    __shared__ int cur[NBUCK];
    __shared__ int wbase[NBUCK];
    __shared__ int stage[CHUNK];

    int tid = threadIdx.x;
    int is64 = flags[1];
    long e0 = (long)blockIdx.x * CHUNK;
    long rem = (long)E - e0;
    int n = (rem < CHUNK) ? (int)rem : CHUNK;
    if (n <= 0) return;

    for (int i = tid; i < NBUCK; i += 256) { hist[i] = 0; cur[i] = 0; }
    __syncthreads();
    for (int j = tid; j < n; j += 256) {
        int d = ldidx(ei, (long)E + e0 + j, is64);
        atomicAdd(&hist[d >> BSHIFT], 1);
    }
    __syncthreads();
    if (tid == 0) {                      // serial excl-scan over 274 entries (cheap)
        int run = 0;
        for (int b = 0; b < NBUCK; ++b) { loff[b] = run; run += hist[b]; }
        loff[NBUCK] = run;
    }
    __syncthreads();
    for (int b = tid; b < NBUCK; b += 256) {
        int h = hist[b];
        int g = (h > 0) ? atomicAdd(&bfill[b], h) : 0;
        wbase[b] = rowptr[b << BSHIFT] + g - loff[b];
    }
    __syncthreads();
    for (int j = tid; j < n; j += 256) {
        int s = ldidx(ei, e0 + j, is64);
        int d = ldidx(ei, (long)E + e0 + j, is64);
        int b = d >> BSHIFT;
        int lpos = loff[b] + atomicAdd(&cur[b], 1);
        stage[lpos] = (s << BSHIFT) | (d & ((1 << BSHIFT) - 1));
    }
    __syncthreads();
    for (int j = tid; j < n; j += 256) {
        int lo = 0, hi = NBUCK;          // find b: loff[b] <= j < loff[b+1]
        while (hi - lo > 1) { int mid = (lo + hi) >> 1; if (loff[mid] <= j) lo = mid; else hi = mid; }
        packed[wbase[lo] + j] = stage[j];
    }
}

// ---------------- fine fill: one block per bucket; all scattered stores confined to one ~18KB region
__global__ __launch_bounds__(256) void finefill_kernel(
    const int* __restrict__ rowptr,
    const int* __restrict__ packed,
    int* __restrict__ srclist,
    int E)
{
    __shared__ int lfill[1 << BSHIFT];
    int b = blockIdx.x;
    int tid = threadIdx.x;
    int nbase = b << BSHIFT;
    int nend = nbase + (1 << BSHIFT); if (nend > NT) nend = NT;
    int nloc = nend - nbase;
    for (int i = tid; i < nloc; i += 256) lfill[i] = rowptr[nbase + i];
    __syncthreads();
    int beg = rowptr[nbase];
    int end = (nend < NT) ? rowptr[nend] : E;
    for (int j = beg + tid; j < end; j += 256) {
        int p = packed[j];
        int dl = p & ((1 << BSHIFT) - 1);
        int pos = atomicAdd(&lfill[dl], 1);
        srclist[pos] = p >> BSHIFT;
    }
}

// ---------------- gather: meanb[n] = mean over incoming edges of x[src]  [8 rows in flight]
__global__ __launch_bounds__(256) void gather_mean(
    const unsigned short* __restrict__ x,
    const int* __restrict__ rowptr,
    const int* __restrict__ cnt,
    const int* __restrict__ srclist,
    unsigned short* __restrict__ meanb)
{
    int wid = (int)(((long)blockIdx.x * 256 + threadIdx.x) >> 6);   // node id
    int lane = threadIdx.x & 63;
    if (wid >= NT) return;
    int beg = rowptr[wid];
    int deg = cnt[wid];
    float acc = 0.f;
    int j0 = 0;
    while (j0 < deg) {
        int m = deg - j0; if (m > 64) m = 64;
        int sv = (lane < m) ? srclist[beg + j0 + lane] : 0;
        int j = 0;
        while (j < m) {
            int c = m - j; if (c > 8) c = 8;
            float v[8];
            #pragma unroll
            for (int q = 0; q < 8; ++q) {                 // issue up to 8 independent loads
                int idx = j + ((q < c) ? q : 0);
                int s = __shfl(sv, idx);
                v[q] = bfu2f(x[(long)s * HD + lane]);
            }
            #pragma unroll
            for (int q = 0; q < 8; ++q) if (q < c) acc += v[q];
            j += c;
        }
        j0 += m;
    }
    float mean = acc / fmaxf((float)deg, 1.0f);
    meanb[(long)wid * HD + lane] = f2bf_raw(mean);
}

// ---------------- combine: out = act( mean @ Wl.T + b + xin @ Wr.T )   [in-place: out may == xin]
template <bool RELU>
__global__ __launch_bounds__(256) void combine_kernel(
    const unsigned short* __restrict__ meanb,
    const unsigned short* __restrict__ xin,
    const void* __restrict__ Wl,
    const void* __restrict__ bias,
    const void* __restrict__ Wr,
    unsigned short* __restrict__ out,
    const int* __restrict__ flags)
{
    __shared__ short8 lWl8[HD * HD / 8];
    __shared__ short8 lWr8[HD * HD / 8];
    __shared__ short8 lmean8[HD * HD / 8];
    __shared__ short8 lx8[HD * HD / 8];
    __shared__ float lb[HD];
    unsigned short* lWl  = (unsigned short*)lWl8;
    unsigned short* lWr  = (unsigned short*)lWr8;
    unsigned short* lmean = (unsigned short*)lmean8;
    unsigned short* lx   = (unsigned short*)lx8;

    int tid = threadIdx.x;
    int isbf = flags[0];
    if (isbf) {
        const short8* wl8 = (const short8*)Wl;
        const short8* wr8 = (const short8*)Wr;
        for (int i = tid; i < HD * HD / 8; i += 256) { lWl8[i] = wl8[i]; lWr8[i] = wr8[i]; }
    } else {
        const floatx4* wlf = (const floatx4*)Wl;
        const floatx4* wrf = (const floatx4*)Wr;
        for (int i = tid; i < HD * HD / 8; i += 256) {
            floatx4 a = wlf[2 * i], b = wlf[2 * i + 1];
            short8 r;
            r[0]=(short)f2bf_raw(a[0]); r[1]=(short)f2bf_raw(a[1]); r[2]=(short)f2bf_raw(a[2]); r[3]=(short)f2bf_raw(a[3]);
            r[4]=(short)f2bf_raw(b[0]); r[5]=(short)f2bf_raw(b[1]); r[6]=(short)f2bf_raw(b[2]); r[7]=(short)f2bf_raw(b[3]);
            lWl8[i] = r;
            a = wrf[2 * i]; b = wrf[2 * i + 1];
            r[0]=(short)f2bf_raw(a[0]); r[1]=(short)f2bf_raw(a[1]); r[2]=(short)f2bf_raw(a[2]); r[3]=(short)f2bf_raw(a[3]);
            r[4]=(short)f2bf_raw(b[0]); r[5]=(short)f2bf_raw(b[1]); r[6]=(short)f2bf_raw(b[2]); r[7]=(short)f2bf_raw(b[3]);
            lWr8[i] = r;
        }
    }
    if (tid < HD) lb[tid] = ldf(bias, tid, isbf);

    int tile = blockIdx.x;                 // 64 nodes per tile; NT = 64*4375 exactly
    long base = (long)tile * HD * HD;
    const short8* mv = (const short8*)(meanb + base);
    const short8* xv = (const short8*)(xin + base);
    for (int i = tid; i < HD * HD / 8; i += 256) { lmean8[i] = mv[i]; lx8[i] = xv[i]; }
    __syncthreads();      // all reads of this tile's xin complete before any in-place write below

    int w = tid >> 6;
    int lane = tid & 63;
    int mrow = lane & 15;
    int quad = lane >> 4;

    short8 am0 = *(const short8*)&lmean[(w * 16 + mrow) * HD + quad * 8];
    short8 am1 = *(const short8*)&lmean[(w * 16 + mrow) * HD + 32 + quad * 8];
    short8 ax0 = *(const short8*)&lx[(w * 16 + mrow) * HD + quad * 8];
    short8 ax1 = *(const short8*)&lx[(w * 16 + mrow) * HD + 32 + quad * 8];

    floatx4 acc[4];
    #pragma unroll
    for (int ht = 0; ht < 4; ++ht) {
        int h = ht * 16 + mrow;
        short8 bl0 = *(const short8*)&lWl[h * HD + quad * 8];
        short8 bl1 = *(const short8*)&lWl[h * HD + 32 + quad * 8];
        short8 br0 = *(const short8*)&lWr[h * HD + quad * 8];
        short8 br1 = *(const short8*)&lWr[h * HD + 32 + quad * 8];
        floatx4 a = {0.f, 0.f, 0.f, 0.f};
        a = __builtin_amdgcn_mfma_f32_16x16x32_bf16(am0, bl0, a, 0, 0, 0);
        a = __builtin_amdgcn_mfma_f32_16x16x32_bf16(am1, bl1, a, 0, 0, 0);
        a = __builtin_amdgcn_mfma_f32_16x16x32_bf16(ax0, br0, a, 0, 0, 0);
        a = __builtin_amdgcn_mfma_f32_16x16x32_bf16(ax1, br1, a, 0, 0, 0);
        acc[ht] = a;
    }

    #pragma unroll
    for (int ht = 0; ht < 4; ++ht) {
        int h = ht * 16 + mrow;
        float bv = lb[h];
        #pragma unroll
        for (int r = 0; r < 4; ++r) {
            int node = w * 16 + quad * 4 + r;
            float v = acc[ht][r] + bv;
            if (RELU) v = fmaxf(v, 0.0f);
            out[base + node * HD + h] = f2bf_raw(v);
        }
    }
}

// ---------------- final: out[e] = dot(x2[u[e]], x2[NU + m[e]])
__global__ __launch_bounds__(256) void dot_kernel(
    const unsigned short* __restrict__ x2,
    const int* __restrict__ eli,
    void* __restrict__ out,
    int EL,
    const int* __restrict__ flags)
{
    long g = ((long)blockIdx.x * 256 + threadIdx.x) >> 6;
    int lane = threadIdx.x & 63;
    if (g >= EL) return;
    int isbf = flags[0];
    int is64 = flags[1];
    int u = ldidx(eli, g, is64);
    int m = ldidx(eli, (long)EL + g, is64);
    float p = bfu2f(x2[(long)u * HD + lane]) * bfu2f(x2[(long)(NU + m) * HD + lane]);
    #pragma unroll
    for (int off = 32; off > 0; off >>= 1) p += __shfl_down(p, off);
    if (lane == 0) {
        if (isbf) ((unsigned short*)out)[g] = f2bf_raw(p);
        else      ((float*)out)[g] = p;
    }
}

extern "C" void kernel_launch(void* const* d_in, const int* in_sizes, int n_in,
                              void* d_out, int out_size, void* d_ws, size_t ws_size,
                              hipStream_t stream)
{
    const void* movie_x   = d_in[0];
    const void* user_emb  = d_in[1];
    const void* movie_emb = d_in[2];
    const void* lin_W     = d_in[3];
    const void* lin_b     = d_in[4];
    const void* W1l       = d_in[5];
    const void* b1        = d_in[6];
    const void* W1r       = d_in[7];
    const void* W2l       = d_in[8];
    const void* b2        = d_in[9];
    const void* W2r       = d_in[10];
    const int* ei  = (const int*)d_in[11];
    const int* eli = (const int*)d_in[12];
    int E  = in_sizes[11] / 2;
    int EL = in_sizes[12] / 2;

    const int NB = (NT + 255) / 256;     // 1094 scan blocks

    char* w = (char*)d_ws;
    unsigned short* xb      = (unsigned short*)w;  w += (size_t)NT * HD * 2;  // 35.84 MB
    unsigned short* meanb   = (unsigned short*)w;  w += (size_t)NT * HD * 2;  // 35.84 MB
    int*            cnt     = (int*)w;             w += (size_t)NT * 4;
    int*            rowptr  = (int*)w;             w += (size_t)NT * 4;
    int*            srclist = (int*)w;             w += (size_t)E * 4;        // 5 MB
    int*            packed  = (int*)w;             w += (size_t)E * 4;        // 5 MB
    int*            bsum    = (int*)w;             w += (size_t)NB * 4;
    int*            bfill   = (int*)w;             w += (size_t)NBUCK * 4;
    int*            flags   = (int*)w;

    const int user_blocks   = (NU * HD / 8) / 256;      // 6250 exactly
    const int movie_blocks  = (NM * 64 + 255) / 256;    // 20000 (wave per movie)
    const int edge_blocks   = (E + 255) / 256;
    const int bucket_blocks = (E + CHUNK - 1) / CHUNK;  // 153
    const int node_blocks   = (NT * HD + 255) / 256;
    const int tile_blocks   = NT / 64;                  // 4375
    const int dot_blocks    = (EL * HD + 255) / 256;    // 125000

    probe_kernel<<<1, 64, 0, stream>>>(user_emb, ei, flags);

    prep_user<<<user_blocks, 256, 0, stream>>>(user_emb, xb, flags);
    prep_movie<<<movie_blocks, 256, 0, stream>>>(movie_x, movie_emb, lin_W, lin_b, xb, flags);

    // CSR build (once; reused by both layers)
    hipMemsetAsync(cnt, 0, (size_t)NT * 4, stream);
    hipMemsetAsync(bfill, 0, (size_t)NBUCK * 4, stream);
    hist_kernel<<<edge_blocks, 256, 0, stream>>>(ei, E, cnt, flags);
    scan1_kernel<<<NB, 256, 0, stream>>>(cnt, bsum);
    scan2_kernel<<<1, 256, 0, stream>>>(bsum, NB);
    scan3_kernel<<<NB, 256, 0, stream>>>(cnt, bsum, rowptr);
    bucket_kernel<<<bucket_blocks, 256, 0, stream>>>(ei, E, rowptr, bfill, packed, flags);
    finefill_kernel<<<NBUCK, 256, 0, stream>>>(rowptr, packed, srclist, E);

    // layer 1
    gather_mean<<<node_blocks, 256, 0, stream>>>(xb, rowptr, cnt, srclist, meanb);
    combine_kernel<true><<<tile_blocks, 256, 0, stream>>>(meanb, xb, W1l, b1, W1r, xb, flags);

    // layer 2
    gather_mean<<<node_blocks, 256, 0, stream>>>(xb, rowptr, cnt, srclist, meanb);
    combine_kernel<false><<<tile_blocks, 256, 0, stream>>>(meanb, xb, W2l, b2, W2r, xb, flags);

    // final edge dot products
    dot_kernel<<<dot_blocks, 256, 0, stream>>>(xb, eli, d_out, EL, flags);
}

// Round 7
// 524.497 us; speedup vs baseline: 2.0859x; 1.1343x over previous
//
#include <hip/hip_runtime.h>
#include <hip/hip_bf16.h>

#define NU 200000
#define NM 80000
#define NT 280000   // NU + NM
#define HD 64
#define FM 20

#define BSHIFT 10
#define NBUCK ((NT + 1023) >> 10)   // 274 buckets of 1024 nodes
#define CHUNK 8192

typedef __attribute__((ext_vector_type(8))) short short8;
typedef __attribute__((ext_vector_type(4))) float floatx4;

__device__ __forceinline__ float bfu2f(unsigned short u) {
    union { unsigned int u; float f; } c; c.u = ((unsigned int)u) << 16; return c.f;
}

__device__ __forceinline__ unsigned short f2bf_raw(float f) {
    union { float f; unsigned int u; } c; c.f = f;
    unsigned int u = c.u + 0x7FFFu + ((c.u >> 16) & 1u);   // round-nearest-even
    return (unsigned short)(u >> 16);
}

__device__ __forceinline__ float ldf(const void* p, long i, int isbf) {
    return isbf ? bfu2f(((const unsigned short*)p)[i]) : ((const float*)p)[i];
}
__device__ __forceinline__ int ldidx(const int* p, long j, int is64) {
    return is64 ? p[2 * j] : p[j];
}

// ---------------- runtime dtype probe -> flags[0]=isbf16, flags[1]=isint64
__global__ void probe_kernel(const void* user_emb, const int* ei, int* flags) {
    int t = threadIdx.x;
    int bad = 0;
    for (int i = t; i < 128; i += 64) {
        unsigned short h = ((const unsigned short*)user_emb)[i];
        unsigned int e = (h >> 7) & 0xFF;
        if (e >= 135) bad = 1;               // |x| >= 256, or Inf/NaN -> not real bf16
    }
    unsigned long long mf = __ballot(bad != 0);
    int odd_nonzero = 0;
    if (t < 16 && ei[2 * t + 1] != 0) odd_nonzero = 1;
    unsigned long long mi = __ballot(odd_nonzero != 0);
    if (t == 0) {
        flags[0] = (mf == 0) ? 1 : 0;
        flags[1] = (mi == 0) ? 1 : 0;
    }
}

// ---------------- prep A: user rows, vectorized copy/convert (8 elems/thread)
__global__ __launch_bounds__(256) void prep_user(
    const void* __restrict__ user_emb,
    unsigned short* __restrict__ xb,
    const int* __restrict__ flags)
{
    long t = (long)blockIdx.x * 256 + threadIdx.x;        // t < NU*HD/8 = 1.6M exactly
    int isbf = flags[0];
    if (isbf) {
        ((short8*)xb)[t] = ((const short8*)user_emb)[t];
    } else {
        floatx4 a = ((const floatx4*)user_emb)[2 * t];
        floatx4 b = ((const floatx4*)user_emb)[2 * t + 1];
        short8 r;
        r[0] = (short)f2bf_raw(a[0]); r[1] = (short)f2bf_raw(a[1]);
        r[2] = (short)f2bf_raw(a[2]); r[3] = (short)f2bf_raw(a[3]);
        r[4] = (short)f2bf_raw(b[0]); r[5] = (short)f2bf_raw(b[1]);
        r[6] = (short)f2bf_raw(b[2]); r[7] = (short)f2bf_raw(b[3]);
        ((short8*)xb)[t] = r;
    }
}

// ---------------- prep B: movie rows. lin_W transposed in LDS; movie_x row via shfl.
__global__ __launch_bounds__(256) void prep_movie(
    const void* __restrict__ movie_x,
    const void* __restrict__ movie_emb,
    const void* __restrict__ lin_W,
    const void* __restrict__ lin_b,
    unsigned short* __restrict__ xb,
    const int* __restrict__ flags)
{
    __shared__ float lWT[FM * HD];   // [k][h] layout -> conflict-free reads
    __shared__ float lb[HD];
    int tid = threadIdx.x;
    int isbf = flags[0];
    for (int i = tid; i < FM * HD; i += 256) {
        int k = i >> 6, h = i & 63;
        lWT[i] = ldf(lin_W, (long)h * FM + k, isbf);
    }
    if (tid < HD) lb[tid] = ldf(lin_b, tid, isbf);
    __syncthreads();

    int m = (blockIdx.x * 256 + tid) >> 6;    // movie id, one wave per movie
    int lane = tid & 63;
    if (m >= NM) return;
    float mxv = (lane < FM) ? ldf(movie_x, (long)m * FM + lane, isbf) : 0.f;
    float acc = lb[lane] + ldf(movie_emb, (long)m * HD + lane, isbf);
    #pragma unroll
    for (int k = 0; k < FM; ++k)
        acc += __shfl(mxv, k) * lWT[k * HD + lane];
    xb[(long)(NU + m) * HD + lane] = f2bf_raw(acc);
}

// ---------------- CSR build ----------------
__global__ __launch_bounds__(256) void hist_kernel(
    const int* __restrict__ ei, int E, int* __restrict__ cnt, const int* __restrict__ flags)
{
    long e = (long)blockIdx.x * 256 + threadIdx.x;
    if (e >= E) return;
    int d = ldidx(ei, (long)E + e, flags[1]);
    atomicAdd(&cnt[d], 1);
}

__global__ __launch_bounds__(256) void scan1_kernel(const int* __restrict__ cnt, int* __restrict__ bsum)
{
    __shared__ int s[256];
    int t = threadIdx.x;
    long i = (long)blockIdx.x * 256 + t;
    s[t] = (i < NT) ? cnt[i] : 0;
    __syncthreads();
    for (int off = 128; off > 0; off >>= 1) {
        if (t < off) s[t] += s[t + off];
        __syncthreads();
    }
    if (t == 0) bsum[blockIdx.x] = s[0];
}

__global__ __launch_bounds__(256) void scan2_kernel(int* __restrict__ bsum, int NB)
{
    __shared__ int chunk[256];
    int t = threadIdx.x;
    int per = (NB + 255) / 256;
    int begin = t * per;
    int end = begin + per; if (end > NB) end = NB; if (begin > NB) begin = NB;
    int sum = 0;
    for (int i = begin; i < end; ++i) sum += bsum[i];
    chunk[t] = sum;
    __syncthreads();
    for (int off = 1; off < 256; off <<= 1) {
        int v = chunk[t];
        if (t >= off) v += chunk[t - off];
        __syncthreads();
        chunk[t] = v;
        __syncthreads();
    }
    int run = (t == 0) ? 0 : chunk[t - 1];
    for (int i = begin; i < end; ++i) {
        int v = bsum[i];
        bsum[i] = run;
        run += v;
    }
}

__global__ __launch_bounds__(256) void scan3_kernel(
    const int* __restrict__ cnt, const int* __restrict__ bsum,
    int* __restrict__ rowptr)
{
    __shared__ int s[256];
    int t = threadIdx.x;
    long i = (long)blockIdx.x * 256 + t;
    int v = (i < NT) ? cnt[i] : 0;
    s[t] = v;
    __syncthreads();
    for (int off = 1; off < 256; off <<= 1) {
        int u = s[t];
        if (t >= off) u += s[t - off];
        __syncthreads();
        s[t] = u;
        __syncthreads();
    }
    if (i < NT) rowptr[i] = bsum[blockIdx.x] + s[t] - v;   // exclusive
}

// ---------------- bucket pass: group edges by dst>>10 into packed buffer (coalesced runs)
// packed entry: (src << 10) | (dst & 1023); bucket b's region = [rowptr[b<<10], ...)
__global__ __launch_bounds__(256) void bucket_kernel(
    const int* __restrict__ ei, int E,
    const int* __restrict__ rowptr,
    int* __restrict__ bfill,           // NBUCK cursors, pre-zeroed
    int* __restrict__ packed,
    const int* __restrict__ flags)
{
    __shared__ int hist[NBUCK];
    __shared__ int loff[NBUCK + 1];
    __shared__ int cur[NBUCK];
    __shared__ int wbase[NBUCK];
    __shared__ int stage[CHUNK];

    int tid = threadIdx.x;
    int is64 = flags[1];
    long e0 = (long)blockIdx.x * CHUNK;
    long rem = (long)E - e0;
    int n = (rem < CHUNK) ? (int)rem : CHUNK;
    if (n <= 0) return;

    for (int i = tid; i < NBUCK; i += 256) { hist[i] = 0; cur[i] = 0; }
    __syncthreads();
    for (int j = tid; j < n; j += 256) {
        int d = ldidx(ei, (long)E + e0 + j, is64);
        atomicAdd(&hist[d >> BSHIFT], 1);
    }
    __syncthreads();
    if (tid == 0) {                      // serial excl-scan over 274 entries (cheap)
        int run = 0;
        for (int b = 0; b < NBUCK; ++b) { loff[b] = run; run += hist[b]; }
        loff[NBUCK] = run;
    }
    __syncthreads();
    for (int b = tid; b < NBUCK; b += 256) {
        int h = hist[b];
        int g = (h > 0) ? atomicAdd(&bfill[b], h) : 0;
        wbase[b] = rowptr[b << BSHIFT] + g - loff[b];
    }
    __syncthreads();
    for (int j = tid; j < n; j += 256) {
        int s = ldidx(ei, e0 + j, is64);
        int d = ldidx(ei, (long)E + e0 + j, is64);
        int b = d >> BSHIFT;
        int lpos = loff[b] + atomicAdd(&cur[b], 1);
        stage[lpos] = (s << BSHIFT) | (d & ((1 << BSHIFT) - 1));
    }
    __syncthreads();
    for (int j = tid; j < n; j += 256) {
        int lo = 0, hi = NBUCK;          // find b: loff[b] <= j < loff[b+1]
        while (hi - lo > 1) { int mid = (lo + hi) >> 1; if (loff[mid] <= j) lo = mid; else hi = mid; }
        packed[wbase[lo] + j] = stage[j];
    }
}

// ---------------- fine fill: one block per bucket; all scattered stores confined to one ~18KB region
__global__ __launch_bounds__(256) void finefill_kernel(
    const int* __restrict__ rowptr,
    const int* __restrict__ packed,
    int* __restrict__ srclist,
    int E)
{
    __shared__ int lfill[1 << BSHIFT];
    int b = blockIdx.x;
    int tid = threadIdx.x;
    int nbase = b << BSHIFT;
    int nend = nbase + (1 << BSHIFT); if (nend > NT) nend = NT;
    int nloc = nend - nbase;
    for (int i = tid; i < nloc; i += 256) lfill[i] = rowptr[nbase + i];
    __syncthreads();
    int beg = rowptr[nbase];
    int end = (nend < NT) ? rowptr[nend] : E;
    for (int j = beg + tid; j < end; j += 256) {
        int p = packed[j];
        int dl = p & ((1 << BSHIFT) - 1);
        int pos = atomicAdd(&lfill[dl], 1);
        srclist[pos] = p >> BSHIFT;
    }
}

// ---------------- gather: meanb[n] = mean over incoming edges of x[src]  [8 rows in flight]
__global__ __launch_bounds__(256) void gather_mean(
    const unsigned short* __restrict__ x,
    const int* __restrict__ rowptr,
    const int* __restrict__ cnt,
    const int* __restrict__ srclist,
    unsigned short* __restrict__ meanb)
{
    int wid = (int)(((long)blockIdx.x * 256 + threadIdx.x) >> 6);   // node id
    int lane = threadIdx.x & 63;
    if (wid >= NT) return;
    int beg = rowptr[wid];
    int deg = cnt[wid];
    float acc = 0.f;
    int j0 = 0;
    while (j0 < deg) {
        int m = deg - j0; if (m > 64) m = 64;
        int sv = (lane < m) ? srclist[beg + j0 + lane] : 0;
        int j = 0;
        while (j < m) {
            int c = m - j; if (c > 8) c = 8;
            float v[8];
            #pragma unroll
            for (int q = 0; q < 8; ++q) {                 // issue up to 8 independent loads
                int idx = j + ((q < c) ? q : 0);
                int s = __shfl(sv, idx);
                v[q] = bfu2f(x[(long)s * HD + lane]);
            }
            #pragma unroll
            for (int q = 0; q < 8; ++q) if (q < c) acc += v[q];
            j += c;
        }
        j0 += m;
    }
    float mean = acc / fmaxf((float)deg, 1.0f);
    meanb[(long)wid * HD + lane] = f2bf_raw(mean);
}

// ---------------- combine: out = act( mean @ Wl.T + b + xin @ Wr.T )   [in-place: out may == xin]
template <bool RELU>
__global__ __launch_bounds__(256) void combine_kernel(
    const unsigned short* __restrict__ meanb,
    const unsigned short* __restrict__ xin,
    const void* __restrict__ Wl,
    const void* __restrict__ bias,
    const void* __restrict__ Wr,
    unsigned short* __restrict__ out,
    const int* __restrict__ flags)
{
    __shared__ short8 lWl8[HD * HD / 8];
    __shared__ short8 lWr8[HD * HD / 8];
    __shared__ short8 lmean8[HD * HD / 8];
    __shared__ short8 lx8[HD * HD / 8];
    __shared__ float lb[HD];
    unsigned short* lWl  = (unsigned short*)lWl8;
    unsigned short* lWr  = (unsigned short*)lWr8;
    unsigned short* lmean = (unsigned short*)lmean8;
    unsigned short* lx   = (unsigned short*)lx8;

    int tid = threadIdx.x;
    int isbf = flags[0];
    if (isbf) {
        const short8* wl8 = (const short8*)Wl;
        const short8* wr8 = (const short8*)Wr;
        for (int i = tid; i < HD * HD / 8; i += 256) { lWl8[i] = wl8[i]; lWr8[i] = wr8[i]; }
    } else {
        const floatx4* wlf = (const floatx4*)Wl;
        const floatx4* wrf = (const floatx4*)Wr;
        for (int i = tid; i < HD * HD / 8; i += 256) {
            floatx4 a = wlf[2 * i], b = wlf[2 * i + 1];
            short8 r;
            r[0]=(short)f2bf_raw(a[0]); r[1]=(short)f2bf_raw(a[1]); r[2]=(short)f2bf_raw(a[2]); r[3]=(short)f2bf_raw(a[3]);
            r[4]=(short)f2bf_raw(b[0]); r[5]=(short)f2bf_raw(b[1]); r[6]=(short)f2bf_raw(b[2]); r[7]=(short)f2bf_raw(b[3]);
            lWl8[i] = r;
            a = wrf[2 * i]; b = wrf[2 * i + 1];
            r[0]=(short)f2bf_raw(a[0]); r[1]=(short)f2bf_raw(a[1]); r[2]=(short)f2bf_raw(a[2]); r[3]=(short)f2bf_raw(a[3]);
            r[4]=(short)f2bf_raw(b[0]); r[5]=(short)f2bf_raw(b[1]); r[6]=(short)f2bf_raw(b[2]); r[7]=(short)f2bf_raw(b[3]);
            lWr8[i] = r;
        }
    }
    if (tid < HD) lb[tid] = ldf(bias, tid, isbf);

    int tile = blockIdx.x;                 // 64 nodes per tile; NT = 64*4375 exactly
    long base = (long)tile * HD * HD;
    const short8* mv = (const short8*)(meanb + base);
    const short8* xv = (const short8*)(xin + base);
    for (int i = tid; i < HD * HD / 8; i += 256) { lmean8[i] = mv[i]; lx8[i] = xv[i]; }
    __syncthreads();      // all reads of this tile's xin complete before any in-place write below

    int w = tid >> 6;
    int lane = tid & 63;
    int mrow = lane & 15;
    int quad = lane >> 4;

    short8 am0 = *(const short8*)&lmean[(w * 16 + mrow) * HD + quad * 8];
    short8 am1 = *(const short8*)&lmean[(w * 16 + mrow) * HD + 32 + quad * 8];
    short8 ax0 = *(const short8*)&lx[(w * 16 + mrow) * HD + quad * 8];
    short8 ax1 = *(const short8*)&lx[(w * 16 + mrow) * HD + 32 + quad * 8];

    floatx4 acc[4];
    #pragma unroll
    for (int ht = 0; ht < 4; ++ht) {
        int h = ht * 16 + mrow;
        short8 bl0 = *(const short8*)&lWl[h * HD + quad * 8];
        short8 bl1 = *(const short8*)&lWl[h * HD + 32 + quad * 8];
        short8 br0 = *(const short8*)&lWr[h * HD + quad * 8];
        short8 br1 = *(const short8*)&lWr[h * HD + 32 + quad * 8];
        floatx4 a = {0.f, 0.f, 0.f, 0.f};
        a = __builtin_amdgcn_mfma_f32_16x16x32_bf16(am0, bl0, a, 0, 0, 0);
        a = __builtin_amdgcn_mfma_f32_16x16x32_bf16(am1, bl1, a, 0, 0, 0);
        a = __builtin_amdgcn_mfma_f32_16x16x32_bf16(ax0, br0, a, 0, 0, 0);
        a = __builtin_amdgcn_mfma_f32_16x16x32_bf16(ax1, br1, a, 0, 0, 0);
        acc[ht] = a;
    }

    #pragma unroll
    for (int ht = 0; ht < 4; ++ht) {
        int h = ht * 16 + mrow;
        float bv = lb[h];
        #pragma unroll
        for (int r = 0; r < 4; ++r) {
            int node = w * 16 + quad * 4 + r;
            float v = acc[ht][r] + bv;
            if (RELU) v = fmaxf(v, 0.0f);
            out[base + node * HD + h] = f2bf_raw(v);
        }
    }
}

// ---------------- final: out[e] = dot(x2[u[e]], x2[NU + m[e]])
// 4 lanes per edge, 16 edges per wave; 16B vector loads; 2-step xor reduce.
__global__ __launch_bounds__(256) void dot_kernel(
    const unsigned short* __restrict__ x2,
    const int* __restrict__ eli,
    void* __restrict__ out,
    int EL,
    const int* __restrict__ flags)
{
    int wid = (blockIdx.x * 256 + threadIdx.x) >> 6;    // global wave id
    long base = (long)wid * 16;                          // first edge of this wave
    if (base >= EL) return;
    int lane = threadIdx.x & 63;
    int isbf = flags[0];
    int is64 = flags[1];

    // lanes 0..15 load u indices, lanes 16..31 load m indices (EL % 16 == 0)
    int idxv = 0;
    if (lane < 16)      idxv = ldidx(eli, base + lane, is64);
    else if (lane < 32) idxv = ldidx(eli, (long)EL + base + (lane - 16), is64);

    int e   = lane >> 2;          // edge slot 0..15
    int seg = lane & 3;           // 16-element segment of the 64-dim row
    int u = __shfl(idxv, e);
    int m = __shfl(idxv, 16 + e);

    const short8* up = (const short8*)(x2 + (long)u * HD + seg * 16);
    const short8* mp = (const short8*)(x2 + (long)(NU + m) * HD + seg * 16);
    short8 a0 = up[0], a1 = up[1];
    short8 b0 = mp[0], b1 = mp[1];

    float p = 0.f;
    #pragma unroll
    for (int j = 0; j < 8; ++j) {
        p += bfu2f((unsigned short)a0[j]) * bfu2f((unsigned short)b0[j]);
        p += bfu2f((unsigned short)a1[j]) * bfu2f((unsigned short)b1[j]);
    }
    p += __shfl_xor(p, 1);
    p += __shfl_xor(p, 2);

    if (seg == 0) {
        long g = base + e;
        if (isbf) ((unsigned short*)out)[g] = f2bf_raw(p);
        else      ((float*)out)[g] = p;
    }
}

extern "C" void kernel_launch(void* const* d_in, const int* in_sizes, int n_in,
                              void* d_out, int out_size, void* d_ws, size_t ws_size,
                              hipStream_t stream)
{
    const void* movie_x   = d_in[0];
    const void* user_emb  = d_in[1];
    const void* movie_emb = d_in[2];
    const void* lin_W     = d_in[3];
    const void* lin_b     = d_in[4];
    const void* W1l       = d_in[5];
    const void* b1        = d_in[6];
    const void* W1r       = d_in[7];
    const void* W2l       = d_in[8];
    const void* b2        = d_in[9];
    const void* W2r       = d_in[10];
    const int* ei  = (const int*)d_in[11];
    const int* eli = (const int*)d_in[12];
    int E  = in_sizes[11] / 2;
    int EL = in_sizes[12] / 2;

    const int NB = (NT + 255) / 256;     // 1094 scan blocks

    char* w = (char*)d_ws;
    unsigned short* xb      = (unsigned short*)w;  w += (size_t)NT * HD * 2;  // 35.84 MB
    unsigned short* meanb   = (unsigned short*)w;  w += (size_t)NT * HD * 2;  // 35.84 MB
    int*            cnt     = (int*)w;             w += (size_t)NT * 4;
    int*            rowptr  = (int*)w;             w += (size_t)NT * 4;
    int*            srclist = (int*)w;             w += (size_t)E * 4;        // 5 MB
    int*            packed  = (int*)w;             w += (size_t)E * 4;        // 5 MB
    int*            bsum    = (int*)w;             w += (size_t)NB * 4;
    int*            bfill   = (int*)w;             w += (size_t)NBUCK * 4;
    int*            flags   = (int*)w;

    const int user_blocks   = (NU * HD / 8) / 256;      // 6250 exactly
    const int movie_blocks  = (NM * 64 + 255) / 256;    // 20000 (wave per movie)
    const int edge_blocks   = (E + 255) / 256;
    const int bucket_blocks = (E + CHUNK - 1) / CHUNK;  // 153
    const int node_blocks   = (NT * HD + 255) / 256;
    const int tile_blocks   = NT / 64;                  // 4375
    const int dot_blocks    = ((EL + 15) / 16 + 3) / 4; // 4 waves/block, 16 edges/wave -> 7813

    probe_kernel<<<1, 64, 0, stream>>>(user_emb, ei, flags);

    prep_user<<<user_blocks, 256, 0, stream>>>(user_emb, xb, flags);
    prep_movie<<<movie_blocks, 256, 0, stream>>>(movie_x, movie_emb, lin_W, lin_b, xb, flags);

    // CSR build (once; reused by both layers)
    hipMemsetAsync(cnt, 0, (size_t)NT * 4, stream);
    hipMemsetAsync(bfill, 0, (size_t)NBUCK * 4, stream);
    hist_kernel<<<edge_blocks, 256, 0, stream>>>(ei, E, cnt, flags);
    scan1_kernel<<<NB, 256, 0, stream>>>(cnt, bsum);
    scan2_kernel<<<1, 256, 0, stream>>>(bsum, NB);
    scan3_kernel<<<NB, 256, 0, stream>>>(cnt, bsum, rowptr);
    bucket_kernel<<<bucket_blocks, 256, 0, stream>>>(ei, E, rowptr, bfill, packed, flags);
    finefill_kernel<<<NBUCK, 256, 0, stream>>>(rowptr, packed, srclist, E);

    // layer 1
    gather_mean<<<node_blocks, 256, 0, stream>>>(xb, rowptr, cnt, srclist, meanb);
    combine_kernel<true><<<tile_blocks, 256, 0, stream>>>(meanb, xb, W1l, b1, W1r, xb, flags);

    // layer 2
    gather_mean<<<node_blocks, 256, 0, stream>>>(xb, rowptr, cnt, srclist, meanb);
    combine_kernel<false><<<tile_blocks, 256, 0, stream>>>(meanb, xb, W2l, b2, W2r, xb, flags);

    // final edge dot products
    dot_kernel<<<dot_blocks, 256, 0, stream>>>(xb, eli, d_out, EL, flags);
}